// Round 17
// baseline (91.506 us; speedup 1.0000x reference)
//
#include <hip/hip_runtime.h>

typedef __attribute__((ext_vector_type(8))) short short8;
typedef __attribute__((ext_vector_type(8))) __bf16 bf16x8;
typedef __attribute__((ext_vector_type(4))) float f32x4;

// sizes
#define B_ 4
#define C_ 64
#define H_ 128
#define W_ 128
#define P_ (H_*W_)      // 16384
#define E_ 16

// ws layout (bytes): only A3 now
#define OFF_A    8652800u

__device__ inline unsigned short f2bf(float f) {
    union { float f; unsigned u; } v; v.f = f;
    unsigned r = v.u + 0x7FFF + ((v.u >> 16) & 1);
    return (unsigned short)(r >> 16);
}

// ---------- build A3 (fragment-linear) from W ----------
// A3 element offset = (g*72 + ks*4 + f)*512 + lane*8 + j   (g = o>>2, f = o&3)
// value = A_orig[row = o*16 + llo][col = ks*32 + lhi*8 + j], col = tap*64 + c
__global__ __launch_bounds__(256) void k_prepA(const float* __restrict__ Wsrc,
                                               unsigned short* __restrict__ A) {
    __shared__ float lw[9216];
    int o = blockIdx.x, t = threadIdx.x;
    const float* src = Wsrc + (size_t)o * 9216; // per o: [j'=c*9+tap][e]
    for (int lin = t; lin < 9216; lin += 256) lw[lin] = src[lin];
    __syncthreads();
    int g = o >> 2, f = o & 3;
    unsigned short* dst = A + ((size_t)g * 72 + f) * 512;
    for (int lin = t; lin < 9216; lin += 256) {
        int ks = lin >> 9, rem = lin & 511;
        int lane = rem >> 3, j = rem & 7;
        int llo = lane & 15, lhi = lane >> 4;
        int col = ks * 32 + lhi * 8 + j;
        int tap = col >> 6, c = col & 63;
        dst[(size_t)ks * 2048 + rem] = f2bf(lw[(c * 9 + tap) * 16 + llo]);
    }
}

// ---------- main kernel: fully self-sufficient per row ----------
// LDS map (67,328 B total, 2 blocks/CU):
//   [0 .. 49,920)      xt region; during P1/P2 holds r1slab [3][16][128] f32 (24,576 B)
//   [49,920 .. 59,136) lcw2: cw re-laid [ep][tap][e] (9,216 B)
//   [59,136 .. 67,328) parapw: pw (P0/P1) then parald [16][128] f32 (8,192 B)
// Phases: P0 stage pw+cw2 | P1 conv1x1+relu -> r1slab | P2 pred2 -> parald
//         | P3 x -> bf16 swizzled xt slab (overwrites r1slab) | P4 main loop.
// P1-P3 are VALU/LDS-heavy and overlap the partner block's MFMA main loop.
__global__ __launch_bounds__(256, 2) void k_main(const float* __restrict__ x,
                                                 const unsigned short* __restrict__ A,
                                                 const float* __restrict__ pw,
                                                 const float* __restrict__ pb,
                                                 const float* __restrict__ cw,
                                                 const float* __restrict__ cb,
                                                 float* __restrict__ out) {
    __shared__ __align__(16) char smem[67328];
    float* r1slab = (float*)smem;                  // [3][16*128]
    float* lcw2   = (float*)(smem + 49920);        // [2304]
    float* parapw = (float*)(smem + 59136);        // pw[1024] then parald[2048]

    int r = blockIdx.x;
    int xcd = r & 7;
    int yl = r >> 3;            // [0,64)
    int rowid = xcd * 64 + yl;  // contiguous 64-row slab per XCD (A stays L2-resident)
    int b = rowid >> 7, y = rowid & 127;

    int tid = threadIdx.x;
    int wave = tid >> 6, lane = tid & 63, lhi = lane >> 4, llo = lane & 15;
    const float* xb = x + (size_t)b * C_ * P_;

    // ---- P0: stage pw (linear) and cw2 (re-laid [ep][tap][e]) ----
    for (int lin = tid; lin < 1024; lin += 256) parapw[lin] = pw[lin];
    for (int lin = tid; lin < 2304; lin += 256) {
        int ep = lin / 144, rem = lin - ep * 144;
        int tap = rem >> 4, e = rem & 15;
        lcw2[lin] = cw[(e * 16 + ep) * 9 + tap];
    }
    __syncthreads();

    // ---- P1: conv1x1 + relu for rows y-1..y+1 -> r1slab (f32 LDS) ----
    for (int task = tid; task < 384; task += 256) {
        int rr = task >> 7, px = task & 127;
        int yy = y + rr - 1;
        float* rrow = r1slab + rr * 2048;
        if (yy >= 0 && yy <= 127) {
            const float* xs = xb + yy * 128 + px;
            float s[16];
#pragma unroll
            for (int e = 0; e < 16; ++e) s[e] = pb[e];
            for (int c = 0; c < 64; ++c) {
                float xv = xs[(size_t)c * P_];
#pragma unroll
                for (int e = 0; e < 16; ++e) s[e] = fmaf(parapw[e * 64 + c], xv, s[e]);
            }
#pragma unroll
            for (int e = 0; e < 16; ++e) rrow[e * 128 + px] = fmaxf(s[e], 0.f);
        } else {
#pragma unroll
            for (int e = 0; e < 16; ++e) rrow[e * 128 + px] = 0.f;
        }
    }
    __syncthreads();

    // ---- P2: pred2 3x3 conv from r1slab -> para (registers, then stored after) ----
    // (parald overwrites pw, which is dead after P1)
    float pout[8];
    int px2 = tid & 127, eg = tid >> 7;
    {
#pragma unroll
        for (int ee = 0; ee < 8; ++ee) pout[ee] = cb[eg * 8 + ee];
        for (int dy = 0; dy < 3; ++dy) {       // slab rows; invalid rows are zero
            for (int dx = 0; dx < 3; ++dx) {
                int xx = px2 + dx - 1;
                if (xx < 0 || xx > 127) continue;
                int tap = dy * 3 + dx;
                const float* rq = r1slab + dy * 2048 + xx;
                const float* cwt = lcw2 + tap * 16 + eg * 8;
#pragma unroll
                for (int ep = 0; ep < 16; ++ep) {
                    float v = rq[ep * 128];
                    const float* cc = cwt + ep * 144;
#pragma unroll
                    for (int ee = 0; ee < 8; ++ee) pout[ee] = fmaf(cc[ee], v, pout[ee]);
                }
            }
        }
    }
    __syncthreads(); // pw reads done everywhere; safe to overwrite with parald
#pragma unroll
    for (int ee = 0; ee < 8; ++ee) parapw[(eg * 8 + ee) * 128 + px2] = pout[ee];
    __syncthreads();
    const float* parald = parapw;

    // ---- P3: x -> bf16 swizzled xt slab (overwrites r1slab region) ----
    {
        short8 z = {0,0,0,0,0,0,0,0};
        for (int task = tid; task < 384; task += 256) {
            int rr = task >> 7, px = task & 127;
            int yy = y + rr - 1;
            int xx = px + 1;
            if (yy >= 0 && yy <= 127) {
                const float* xs = xb + yy * 128 + px;
#pragma unroll
                for (int cc = 0; cc < 8; ++cc) {
                    short8 v;
#pragma unroll
                    for (int j = 0; j < 8; ++j) v[j] = (short)f2bf(xs[(size_t)(cc * 8 + j) * P_]);
                    int lb = rr * 16640 + xx * 128 + ((cc * 16) ^ ((xx & 7) << 4));
                    *(short8*)(smem + lb) = v;
                }
            } else {
#pragma unroll
                for (int cc = 0; cc < 8; ++cc) {
                    int lb = rr * 16640 + xx * 128 + ((cc * 16) ^ ((xx & 7) << 4));
                    *(short8*)(smem + lb) = z;
                }
            }
            if (px == 0) {
#pragma unroll
                for (int cc = 0; cc < 8; ++cc)
                    *(short8*)(smem + rr * 16640 + (cc * 16)) = z;       // xx=0, swz 0
            }
            if (px == 127) {
#pragma unroll
                for (int cc = 0; cc < 8; ++cc)
                    *(short8*)(smem + rr * 16640 + 129 * 128 + ((cc * 16) ^ 16)) = z; // xx=129
            }
        }
    }
    __syncthreads();

    float* po = out + (size_t)b * 64 * P_ + y * 128;

    // precomputed LDS read vaddrs: qv[parity][kw]; full addr = qv + kh*16640 + pg*2048
    int qv[2][3];
#pragma unroll
    for (int kw = 0; kw < 3; ++kw) {
        int rowi = llo + kw;
        int base0 = rowi * 128 + ((lhi * 16) ^ ((rowi & 7) << 4));
        qv[0][kw] = base0;
        qv[1][kw] = base0 ^ 64;
    }
    const char* ldsc = (const char*)smem;

#define PF_AF(dst, KS) do { \
    _Pragma("unroll") \
    for (int f_ = 0; f_ < 4; ++f_) \
        dst[f_] = *(const bf16x8*)(Agl + (KS) * 2048 + f_ * 512); \
    __builtin_amdgcn_sched_barrier(0); \
} while (0)

// one half-body: prefetch A for PFKS into AFP (distance 2), compute with AFU
#define HALF(AFU, AFP, PFKS, PAR, KW) do { \
    PF_AF(AFP, PFKS); \
    const char* bp = bprow + qv[PAR][KW]; \
    bf16x8 bf[8]; \
    _Pragma("unroll") \
    for (int pg_ = 0; pg_ < 8; ++pg_) \
        bf[pg_] = *(const bf16x8*)(bp + pg_ * 2048); \
    __builtin_amdgcn_s_setprio(1); \
    _Pragma("unroll") \
    for (int f_ = 0; f_ < 4; ++f_) \
    _Pragma("unroll") \
    for (int pg_ = 0; pg_ < 8; ++pg_) \
        acc[f_][pg_] = __builtin_amdgcn_mfma_f32_16x16x32_bf16(AFU[f_], bf[pg_], acc[f_][pg_], 0, 0, 0); \
    __builtin_amdgcn_s_setprio(0); \
} while (0)

#pragma unroll 1
    for (int chunk = 0; chunk < 4; ++chunk) {
        int obase = chunk * 16 + wave * 4;
        int g = obase >> 2; // o-group index into A3 (= chunk*4 + wave)
        const unsigned short* Agl = A + (size_t)g * 36864 + lane * 8;

        f32x4 acc[4][8];
#pragma unroll
        for (int f = 0; f < 4; ++f)
#pragma unroll
            for (int pg = 0; pg < 8; ++pg) acc[f][pg] = (f32x4){0.f, 0.f, 0.f, 0.f};

        bf16x8 afA[4], afB[4], afC[4];
        // prologue: A-frags for ks=0,1 (distance-2 pipeline fill)
        PF_AF(afA, 0);
        PF_AF(afB, 1);

#pragma unroll 1
        for (int kh = 0; kh < 3; ++kh) {
            const int ksc = kh * 6;
            const char* bprow = ldsc + kh * 16640;
            // kh=2 prefetches ks 18,19: overread into ws beyond this g's A3
            // slice, never consumed.
            HALF(afA, afC, ksc + 2, 0, 0);
            HALF(afB, afA, ksc + 3, 1, 0);
            HALF(afC, afB, ksc + 4, 0, 1);
            HALF(afA, afC, ksc + 5, 1, 1);
            HALF(afB, afA, ksc + 6, 0, 2);
            HALF(afC, afB, ksc + 7, 1, 2);
        }

        // epilogue: multiply rows (e) by para[e,p] (from LDS), reduce over e
        float pvv[8][4];
#pragma unroll
        for (int pg = 0; pg < 8; ++pg)
#pragma unroll
            for (int rr = 0; rr < 4; ++rr)
                pvv[pg][rr] = parald[(lhi * 4 + rr) * 128 + pg * 16 + llo];

#pragma unroll
        for (int f = 0; f < 4; ++f) {
            int o = obase + f;
#pragma unroll
            for (int pg = 0; pg < 8; ++pg) {
                float s = acc[f][pg][0] * pvv[pg][0] + acc[f][pg][1] * pvv[pg][1] +
                          acc[f][pg][2] * pvv[pg][2] + acc[f][pg][3] * pvv[pg][3];
                s += __shfl_xor(s, 16);
                s += __shfl_xor(s, 32);
                if (lhi == 0)
                    __builtin_nontemporal_store(s, &po[(size_t)o * P_ + pg * 16 + llo]);
            }
        }
    }
#undef PF_AF
#undef HALF
}

extern "C" void kernel_launch(void* const* d_in, const int* in_sizes, int n_in,
                              void* d_out, int out_size, void* d_ws, size_t ws_size,
                              hipStream_t stream) {
    const float* x  = (const float*)d_in[0];
    const float* W  = (const float*)d_in[1];
    const float* pw = (const float*)d_in[2];
    const float* pb = (const float*)d_in[3];
    const float* cw = (const float*)d_in[4];
    const float* cb = (const float*)d_in[5];
    float* out = (float*)d_out;
    char* ws = (char*)d_ws;
    unsigned short* Am = (unsigned short*)(ws + OFF_A);

    hipLaunchKernelGGL(k_prepA, dim3(64), dim3(256), 0, stream, W, Am);
    hipLaunchKernelGGL(k_main, dim3(512), dim3(256), 0, stream, x, Am, pw, pb, cw, cb, out);
}

// Round 18
// 90.638 us; speedup vs baseline: 1.0096x; 1.0096x over previous
//
#include <hip/hip_runtime.h>

typedef __attribute__((ext_vector_type(8))) short short8;
typedef __attribute__((ext_vector_type(8))) __bf16 bf16x8;
typedef __attribute__((ext_vector_type(16))) float f32x16;

// sizes
#define B_ 4
#define C_ 64
#define H_ 128
#define W_ 128
#define P_ (H_*W_)      // 16384
#define E_ 16

// ws layout (bytes)
#define OFF_A    8652800u
#define OFF_R1   9832448u

__device__ inline unsigned short f2bf(float f) {
    union { float f; unsigned u; } v; v.f = f;
    unsigned r = v.u + 0x7FFF + ((v.u >> 16) & 1);
    return (unsigned short)(r >> 16);
}

// ---------- merged prep kernel: transpose+pad+conv1x1 (blocks 0..255, 2 rows
// each) and A4 build (blocks 256..319). ----------
// A4 (for 32x32x16 MFMA): element offset = (mt*36 + kstep)*512 + lane*8 + j
//   mt = row-tile (32 rows of o*16+e), lane: i = lane&31 = row in tile,
//   k = (lane>>5)*8 + j within the K=16 step.  value = A_orig[row][kstep*16 + k]
//   where A_orig[row=o*16+e][col=tap*64+c] = Wsrc[o*9216 + (c*9+tap)*16 + e].
__global__ __launch_bounds__(256) void k_prep(const float* __restrict__ x,
                                              unsigned short* __restrict__ xt,
                                              const float* __restrict__ pw,
                                              const float* __restrict__ pb,
                                              float* __restrict__ r1,
                                              const float* __restrict__ Wsrc,
                                              unsigned short* __restrict__ A) {
    __shared__ float smem[9216];
    int t = threadIdx.x;
    if (blockIdx.x < 256) {
        // ---- transpose + pad + conv1x1+relu, two image rows per block ----
        float* lpw = smem;          // [1024]
        float* lpb = smem + 1024;   // [16]
        for (int lin = t; lin < 1024; lin += 256) lpw[lin] = pw[lin];
        if (t < 16) lpb[t] = pb[t];
        __syncthreads();

        int rowid = blockIdx.x * 2 + (t >> 7);
        int b = rowid >> 7, y = rowid & 127;
        int tt = t & 127; // x coordinate

        const float* src = x + (size_t)b * C_ * P_ + y * W_ + tt;
        unsigned short* dst = xt + ((size_t)(b * 130 + y + 1) * 130 + tt + 1) * 64;
        float s[16];
#pragma unroll
        for (int e = 0; e < 16; ++e) s[e] = lpb[e];
#pragma unroll
        for (int i = 0; i < 8; ++i) {
            short8 v;
#pragma unroll
            for (int j = 0; j < 8; ++j) {
                float xv = src[(size_t)(i * 8 + j) * P_];
                v[j] = (short)f2bf(xv);
#pragma unroll
                for (int e = 0; e < 16; ++e) s[e] = fmaf(lpw[e * 64 + i * 8 + j], xv, s[e]);
            }
            ((short8*)dst)[i] = v;
        }
        float* rd = r1 + (size_t)b * 16 * P_ + y * 128 + tt;
#pragma unroll
        for (int e = 0; e < 16; ++e) rd[(size_t)e * P_] = fmaxf(s[e], 0.f);

        short8 z = {0,0,0,0,0,0,0,0};
        if (tt < 16) {
            int col = (tt >> 3) * 129, i = tt & 7;
            unsigned short* bp = xt + ((size_t)(b * 130 + y + 1) * 130 + col) * 64;
            ((short8*)bp)[i] = z;
        }
        if (y == 0 || y == 127) {
            int prow = (y == 0) ? 0 : 129;
            unsigned short* rp = xt + (size_t)(b * 130 + prow) * 130 * 64;
            for (int ci = tt; ci < 1040; ci += 128) ((short8*)rp)[ci] = z;
        }
    } else {
        // ---- A4 build: o = blockIdx - 256; mt = o>>1, rows (o&1)*16 + e ----
        int o = blockIdx.x - 256;
        const float* src = Wsrc + (size_t)o * 9216; // per o: [j'=c*9+tap][e]
        for (int lin = t; lin < 9216; lin += 256) smem[lin] = src[lin];
        __syncthreads();
        int mt = o >> 1, lo = (o & 1) * 16;
        for (int lin = t; lin < 9216; lin += 256) {
            int kstep = lin >> 8;          // 36 steps x 256 elems
            int rem = lin & 255;
            int e = rem >> 4, kk = rem & 15;
            int hi2 = kk >> 3, j = kk & 7;
            int col = kstep * 16 + kk;
            int tap = col >> 6, c = col & 63;
            int lane = hi2 * 32 + lo + e;
            A[((size_t)(mt * 36 + kstep)) * 512 + lane * 8 + j] =
                f2bf(smem[(c * 9 + tap) * 16 + e]);
        }
    }
}

// ---------- main fused kernel ----------
// R16 structure (fused pred2 prologue from global r1, 2 blocks/CU) with the
// MFMA shape switched to 32x32x16 (2382+ TF vs 2075; half the instruction
// count at identical load count). Wave owns 2 M-tiles (mt, 4 o's) x 128 px
// (4 N-tiles of 32) per chunk: acc[2][4] f32x16 = 128 AGPR. 36 K=16 steps,
// af double-buffered, 4 sub-steps per (kh,kw).
__global__ __launch_bounds__(256, 2) void k_main(const unsigned short* __restrict__ xt,
                                                 const unsigned short* __restrict__ A,
                                                 const float* __restrict__ r1,
                                                 const float* __restrict__ cw,
                                                 const float* __restrict__ cb,
                                                 float* __restrict__ out) {
    __shared__ unsigned short lds[3 * 130 * 64]; // 49,920 B (xt rows)
    __shared__ float lcw2[2304];                 // cw as [ep][tap][e]
    __shared__ float parald[16 * 128];           // para for this row
    int r = blockIdx.x;
    int xcd = r & 7;
    int yl = r >> 3;            // [0,64)
    int rowid = xcd * 64 + yl;  // contiguous 64-row slab per XCD
    int b = rowid >> 7, y = rowid & 127;

    int tid = threadIdx.x;
    int wave = tid >> 6, lane = tid & 63;
    int l31 = lane & 31, hi = lane >> 5;

    // stage 3 padded xt rows (y..y+2), swizzle byte ^= ((xx&7)<<4)
    const unsigned short* xrow = xt + (size_t)(b * 130 + y) * 130 * 64;
    for (int ci = tid; ci < 3120; ci += 256) {
        int row = ci / 1040, rem = ci - row * 1040;
        int xx = rem >> 3, cc = rem & 7;
        short8 v = *(const short8*)(xrow + ((size_t)row * 130 + xx) * 64 + cc * 8);
        int lb = row * 16640 + xx * 128 + ((cc * 16) ^ ((xx & 7) << 4));
        *(short8*)((char*)lds + lb) = v;
    }
    // stage cw re-laid: lcw2[(ep*9+tap)*16 + e] = cw[(e*16+ep)*9 + tap]
    for (int lin = tid; lin < 2304; lin += 256) {
        int ep = lin / 144, rem = lin - ep * 144;
        int tap = rem >> 4, e = rem & 15;
        lcw2[lin] = cw[(e * 16 + ep) * 9 + tap];
    }
    __syncthreads();

    // ---- fused pred2: para[e][px] for row y, 2 threads/px (8 e's each) ----
    {
        int px = tid & 127, eg = tid >> 7;
        const float* r1b = r1 + (size_t)b * 16 * P_;
        float s[8];
#pragma unroll
        for (int ee = 0; ee < 8; ++ee) s[ee] = cb[eg * 8 + ee];
        for (int dy = 0; dy < 3; ++dy) {
            int yy = y + dy - 1;
            if (yy < 0 || yy > 127) continue;
            for (int dx = 0; dx < 3; ++dx) {
                int xx = px + dx - 1;
                if (xx < 0 || xx > 127) continue;
                int tap = dy * 3 + dx;
                const float* rq = r1b + yy * 128 + xx;
                const float* cwt = lcw2 + tap * 16 + eg * 8;
#pragma unroll
                for (int ep = 0; ep < 16; ++ep) {
                    float v = rq[(size_t)ep * P_];
                    const float* cc = cwt + ep * 144;
#pragma unroll
                    for (int ee = 0; ee < 8; ++ee) s[ee] = fmaf(cc[ee], v, s[ee]);
                }
            }
        }
#pragma unroll
        for (int ee = 0; ee < 8; ++ee) parald[(eg * 8 + ee) * 128 + px] = s[ee];
    }
    __syncthreads();

    float* po = out + (size_t)b * 64 * P_ + y * 128;
    const char* ldsc = (const char*)lds;

    // chunk-invariant para values: pv[nt][v] for e=(v&3)+4*hi+8*(v>>2), px=nt*32+l31
    float pv[4][8];
#pragma unroll
    for (int nt = 0; nt < 4; ++nt)
#pragma unroll
        for (int v = 0; v < 8; ++v)
            pv[nt][v] = parald[((v & 3) + 4 * hi + 8 * (v >> 2)) * 128 + nt * 32 + l31];

#define PF_AF(dst, S) do { \
    dst[0] = *(const bf16x8*)(Agl + (S) * 512); \
    dst[1] = *(const bf16x8*)(Agl + 18432 + (S) * 512); \
    __builtin_amdgcn_sched_barrier(0); \
} while (0)

// one K=16 sub-step: compute with AFU, prefetch step S+1 into AFP,
// bf addr = bprow + nt*4096 + Q
#define SUB(AFU, AFP, S, Q) do { \
    PF_AF(AFP, (S) + 1); \
    bf16x8 bf[4]; \
    _Pragma("unroll") \
    for (int nt_ = 0; nt_ < 4; ++nt_) \
        bf[nt_] = *(const bf16x8*)(bprow + nt_ * 4096 + (Q)); \
    __builtin_amdgcn_s_setprio(1); \
    _Pragma("unroll") \
    for (int f_ = 0; f_ < 2; ++f_) \
    _Pragma("unroll") \
    for (int nt_ = 0; nt_ < 4; ++nt_) \
        acc[f_][nt_] = __builtin_amdgcn_mfma_f32_32x32x16_bf16(AFU[f_], bf[nt_], acc[f_][nt_], 0, 0, 0); \
    __builtin_amdgcn_s_setprio(0); \
} while (0)

#pragma unroll 1
    for (int chunk = 0; chunk < 4; ++chunk) {
        int mtb = chunk * 8 + wave * 2;
        const unsigned short* Agl = A + (size_t)mtb * 18432 + lane * 8;

        f32x16 acc[2][4];
#pragma unroll
        for (int f = 0; f < 2; ++f)
#pragma unroll
            for (int nt = 0; nt < 4; ++nt)
#pragma unroll
                for (int vv = 0; vv < 16; ++vv) acc[f][nt][vv] = 0.f;

        bf16x8 afA[2], afB[2];
        PF_AF(afA, 0);

#pragma unroll 1
        for (int kh = 0; kh < 3; ++kh) {
            const char* bprow = ldsc + kh * 16640;
#pragma unroll 1
            for (int kw = 0; kw < 3; ++kw) {
                int xk = l31 + kw;
                int rb = xk * 128, swz = (xk & 7) << 4, h16 = hi * 16;
                int q0 = rb + ((h16) ^ swz);
                int q1 = rb + ((32 + h16) ^ swz);
                int q2 = rb + ((64 + h16) ^ swz);
                int q3 = rb + ((96 + h16) ^ swz);
                int sb = (kh * 3 + kw) * 4;
                // 4 sub-steps; final prefetch (S=36) is an in-ws overread,
                // never consumed.
                SUB(afA, afB, sb + 0, q0);
                SUB(afB, afA, sb + 1, q1);
                SUB(afA, afB, sb + 2, q2);
                SUB(afB, afA, sb + 3, q3);
            }
        }

        // epilogue: rows 0..15 of acc tile = o_even (e=(v&3)+4hi+8(v>>2)),
        // rows 16..31 = o_odd. Reduce e with para, fold hi halves via shfl.
        int obase = mtb * 2;
#pragma unroll
        for (int f = 0; f < 2; ++f) {
            int oe = obase + 2 * f;
#pragma unroll
            for (int nt = 0; nt < 4; ++nt) {
                float se = 0.f, so = 0.f;
#pragma unroll
                for (int v = 0; v < 8; ++v) {
                    se = fmaf(acc[f][nt][v], pv[nt][v], se);
                    so = fmaf(acc[f][nt][v + 8], pv[nt][v], so);
                }
                se += __shfl_xor(se, 32);
                so += __shfl_xor(so, 32);
                int od = hi ? (oe + 1) : oe;
                float sv = hi ? so : se;
                __builtin_nontemporal_store(sv, &po[(size_t)od * P_ + nt * 32 + l31]);
            }
        }
    }
#undef PF_AF
#undef SUB
}

extern "C" void kernel_launch(void* const* d_in, const int* in_sizes, int n_in,
                              void* d_out, int out_size, void* d_ws, size_t ws_size,
                              hipStream_t stream) {
    const float* x  = (const float*)d_in[0];
    const float* W  = (const float*)d_in[1];
    const float* pw = (const float*)d_in[2];
    const float* pb = (const float*)d_in[3];
    const float* cw = (const float*)d_in[4];
    const float* cb = (const float*)d_in[5];
    float* out = (float*)d_out;
    char* ws = (char*)d_ws;
    unsigned short* xt = (unsigned short*)ws;
    unsigned short* Am = (unsigned short*)(ws + OFF_A);
    float* r1   = (float*)(ws + OFF_R1);

    hipLaunchKernelGGL(k_prep, dim3(320), dim3(256), 0, stream, x, xt, pw, pb, r1, W, Am);
    hipLaunchKernelGGL(k_main, dim3(512), dim3(256), 0, stream, xt, Am, r1, cw, cb, out);
}

// Round 19
// 89.106 us; speedup vs baseline: 1.0269x; 1.0172x over previous
//
#include <hip/hip_runtime.h>

typedef __attribute__((ext_vector_type(8))) short short8;
typedef __attribute__((ext_vector_type(8))) __bf16 bf16x8;
typedef __attribute__((ext_vector_type(16))) float f32x16;

// sizes
#define B_ 4
#define C_ 64
#define H_ 128
#define W_ 128
#define P_ (H_*W_)      // 16384
#define E_ 16

// ws layout (bytes)
#define OFF_A    8652800u
#define OFF_R1   9832448u

__device__ inline unsigned short f2bf(float f) {
    union { float f; unsigned u; } v; v.f = f;
    unsigned r = v.u + 0x7FFF + ((v.u >> 16) & 1);
    return (unsigned short)(r >> 16);
}

// ---------- merged prep kernel: transpose+pad+conv1x1 (blocks 0..255, 2 rows
// each) and A4 build (blocks 256..319). ----------
// A4 (for 32x32x16 MFMA): element offset = (mt*36 + kstep)*512 + lane*8 + j
//   mt = row-tile (32 rows of o*16+e), lane: i = lane&31 = row in tile,
//   k = (lane>>5)*8 + j within the K=16 step.  value = A_orig[row][kstep*16 + k]
__global__ __launch_bounds__(256) void k_prep(const float* __restrict__ x,
                                              unsigned short* __restrict__ xt,
                                              const float* __restrict__ pw,
                                              const float* __restrict__ pb,
                                              float* __restrict__ r1,
                                              const float* __restrict__ Wsrc,
                                              unsigned short* __restrict__ A) {
    __shared__ float smem[9216];
    int t = threadIdx.x;
    if (blockIdx.x < 256) {
        // ---- transpose + pad + conv1x1+relu, two image rows per block ----
        float* lpw = smem;          // [1024]
        float* lpb = smem + 1024;   // [16]
        for (int lin = t; lin < 1024; lin += 256) lpw[lin] = pw[lin];
        if (t < 16) lpb[t] = pb[t];
        __syncthreads();

        int rowid = blockIdx.x * 2 + (t >> 7);
        int b = rowid >> 7, y = rowid & 127;
        int tt = t & 127; // x coordinate

        const float* src = x + (size_t)b * C_ * P_ + y * W_ + tt;
        unsigned short* dst = xt + ((size_t)(b * 130 + y + 1) * 130 + tt + 1) * 64;
        float s[16];
#pragma unroll
        for (int e = 0; e < 16; ++e) s[e] = lpb[e];
#pragma unroll
        for (int i = 0; i < 8; ++i) {
            short8 v;
#pragma unroll
            for (int j = 0; j < 8; ++j) {
                float xv = src[(size_t)(i * 8 + j) * P_];
                v[j] = (short)f2bf(xv);
#pragma unroll
                for (int e = 0; e < 16; ++e) s[e] = fmaf(lpw[e * 64 + i * 8 + j], xv, s[e]);
            }
            ((short8*)dst)[i] = v;
        }
        float* rd = r1 + (size_t)b * 16 * P_ + y * 128 + tt;
#pragma unroll
        for (int e = 0; e < 16; ++e) rd[(size_t)e * P_] = fmaxf(s[e], 0.f);

        short8 z = {0,0,0,0,0,0,0,0};
        if (tt < 16) {
            int col = (tt >> 3) * 129, i = tt & 7;
            unsigned short* bp = xt + ((size_t)(b * 130 + y + 1) * 130 + col) * 64;
            ((short8*)bp)[i] = z;
        }
        if (y == 0 || y == 127) {
            int prow = (y == 0) ? 0 : 129;
            unsigned short* rp = xt + (size_t)(b * 130 + prow) * 130 * 64;
            for (int ci = tt; ci < 1040; ci += 128) ((short8*)rp)[ci] = z;
        }
    } else {
        // ---- A4 build: o = blockIdx - 256; mt = o>>1, rows (o&1)*16 + e ----
        int o = blockIdx.x - 256;
        const float* src = Wsrc + (size_t)o * 9216; // per o: [j'=c*9+tap][e]
        for (int lin = t; lin < 9216; lin += 256) smem[lin] = src[lin];
        __syncthreads();
        int mt = o >> 1, lo = (o & 1) * 16;
        for (int lin = t; lin < 9216; lin += 256) {
            int kstep = lin >> 8;          // 36 steps x 256 elems
            int rem = lin & 255;
            int e = rem >> 4, kk = rem & 15;
            int hi2 = kk >> 3, j = kk & 7;
            int col = kstep * 16 + kk;
            int tap = col >> 6, c = col & 63;
            int lane = hi2 * 32 + lo + e;
            A[((size_t)(mt * 36 + kstep)) * 512 + lane * 8 + j] =
                f2bf(smem[(c * 9 + tap) * 16 + e]);
        }
    }
}

// ---------- main fused kernel ----------
// R18 (32x32x16 MFMA, half the instruction count) + R19 fix: LDS xt slab
// stored channel-granule-major [row][g=c/8][px][8ch] so the 32-pixel B-read
// is 32 lanes x consecutive 16B = inherently conflict-free (no XOR swizzle).
// Same 16,640 B/row. Stager writes are bank-balanced ((2cc+xx) mod 8).
__global__ __launch_bounds__(256, 2) void k_main(const unsigned short* __restrict__ xt,
                                                 const unsigned short* __restrict__ A,
                                                 const float* __restrict__ r1,
                                                 const float* __restrict__ cw,
                                                 const float* __restrict__ cb,
                                                 float* __restrict__ out) {
    __shared__ unsigned short lds[3 * 130 * 64]; // 49,920 B (xt slab)
    __shared__ float lcw2[2304];                 // cw as [ep][tap][e]
    __shared__ float parald[16 * 128];           // para for this row
    int r = blockIdx.x;
    int xcd = r & 7;
    int yl = r >> 3;            // [0,64)
    int rowid = xcd * 64 + yl;  // contiguous 64-row slab per XCD
    int b = rowid >> 7, y = rowid & 127;

    int tid = threadIdx.x;
    int wave = tid >> 6, lane = tid & 63;
    int l31 = lane & 31, hi = lane >> 5;

    // stage 3 padded xt rows (y..y+2) -> granule-major slab:
    // lds byte addr = row*16640 + cc*2080 + xx*16   (cc = channel granule)
    const unsigned short* xrow = xt + (size_t)(b * 130 + y) * 130 * 64;
    for (int ci = tid; ci < 3120; ci += 256) {
        int row = ci / 1040, rem = ci - row * 1040;
        int xx = rem >> 3, cc = rem & 7;
        short8 v = *(const short8*)(xrow + ((size_t)row * 130 + xx) * 64 + cc * 8);
        int lb = row * 16640 + cc * 2080 + xx * 16;
        *(short8*)((char*)lds + lb) = v;
    }
    // stage cw re-laid: lcw2[(ep*9+tap)*16 + e] = cw[(e*16+ep)*9 + tap]
    for (int lin = tid; lin < 2304; lin += 256) {
        int ep = lin / 144, rem = lin - ep * 144;
        int tap = rem >> 4, e = rem & 15;
        lcw2[lin] = cw[(e * 16 + ep) * 9 + tap];
    }
    __syncthreads();

    // ---- fused pred2: para[e][px] for row y, 2 threads/px (8 e's each) ----
    {
        int px = tid & 127, eg = tid >> 7;
        const float* r1b = r1 + (size_t)b * 16 * P_;
        float s[8];
#pragma unroll
        for (int ee = 0; ee < 8; ++ee) s[ee] = cb[eg * 8 + ee];
        for (int dy = 0; dy < 3; ++dy) {
            int yy = y + dy - 1;
            if (yy < 0 || yy > 127) continue;
            for (int dx = 0; dx < 3; ++dx) {
                int xx = px + dx - 1;
                if (xx < 0 || xx > 127) continue;
                int tap = dy * 3 + dx;
                const float* rq = r1b + yy * 128 + xx;
                const float* cwt = lcw2 + tap * 16 + eg * 8;
#pragma unroll
                for (int ep = 0; ep < 16; ++ep) {
                    float v = rq[(size_t)ep * P_];
                    const float* cc = cwt + ep * 144;
#pragma unroll
                    for (int ee = 0; ee < 8; ++ee) s[ee] = fmaf(cc[ee], v, s[ee]);
                }
            }
        }
#pragma unroll
        for (int ee = 0; ee < 8; ++ee) parald[(eg * 8 + ee) * 128 + px] = s[ee];
    }
    __syncthreads();

    float* po = out + (size_t)b * 64 * P_ + y * 128;
    const char* ldsc = (const char*)lds;

    // chunk-invariant para values: pv[nt][v] for e=(v&3)+4*hi+8*(v>>2), px=nt*32+l31
    float pv[4][8];
#pragma unroll
    for (int nt = 0; nt < 4; ++nt)
#pragma unroll
        for (int v = 0; v < 8; ++v)
            pv[nt][v] = parald[((v & 3) + 4 * hi + 8 * (v >> 2)) * 128 + nt * 32 + l31];

#define PF_AF(dst, S) do { \
    dst[0] = *(const bf16x8*)(Agl + (S) * 512); \
    dst[1] = *(const bf16x8*)(Agl + 18432 + (S) * 512); \
    __builtin_amdgcn_sched_barrier(0); \
} while (0)

// one K=16 sub-step: compute with AFU, prefetch step S+1 into AFP.
// bf addr = bprow + (2s+hi)*2080 + (l31+kw)*16 + nt*512  (granule-major slab)
#define SUB(AFU, AFP, S, Q) do { \
    PF_AF(AFP, (S) + 1); \
    bf16x8 bf[4]; \
    _Pragma("unroll") \
    for (int nt_ = 0; nt_ < 4; ++nt_) \
        bf[nt_] = *(const bf16x8*)(bprow + (Q) + nt_ * 512); \
    __builtin_amdgcn_s_setprio(1); \
    _Pragma("unroll") \
    for (int f_ = 0; f_ < 2; ++f_) \
    _Pragma("unroll") \
    for (int nt_ = 0; nt_ < 4; ++nt_) \
        acc[f_][nt_] = __builtin_amdgcn_mfma_f32_32x32x16_bf16(AFU[f_], bf[nt_], acc[f_][nt_], 0, 0, 0); \
    __builtin_amdgcn_s_setprio(0); \
} while (0)

#pragma unroll 1
    for (int chunk = 0; chunk < 4; ++chunk) {
        int mtb = chunk * 8 + wave * 2;
        const unsigned short* Agl = A + (size_t)mtb * 18432 + lane * 8;

        f32x16 acc[2][4];
#pragma unroll
        for (int f = 0; f < 2; ++f)
#pragma unroll
            for (int nt = 0; nt < 4; ++nt)
#pragma unroll
                for (int vv = 0; vv < 16; ++vv) acc[f][nt][vv] = 0.f;

        bf16x8 afA[2], afB[2];
        PF_AF(afA, 0);

#pragma unroll 1
        for (int kh = 0; kh < 3; ++kh) {
            const char* bprow = ldsc + kh * 16640;
#pragma unroll 1
            for (int kw = 0; kw < 3; ++kw) {
                int pxb = (l31 + kw) * 16 + hi * 2080;
                int sb = (kh * 3 + kw) * 4;
                // 4 sub-steps (channel granules 2s, 2s+1); final prefetch
                // (S=36) is an in-ws overread, never consumed.
                SUB(afA, afB, sb + 0, pxb);
                SUB(afB, afA, sb + 1, pxb + 2 * 2080);
                SUB(afA, afB, sb + 2, pxb + 4 * 2080);
                SUB(afB, afA, sb + 3, pxb + 6 * 2080);
            }
        }

        // epilogue: rows 0..15 of acc tile = o_even (e=(v&3)+4hi+8(v>>2)),
        // rows 16..31 = o_odd. Reduce e with para, fold hi halves via shfl.
        int obase = mtb * 2;
#pragma unroll
        for (int f = 0; f < 2; ++f) {
            int oe = obase + 2 * f;
#pragma unroll
            for (int nt = 0; nt < 4; ++nt) {
                float se = 0.f, so = 0.f;
#pragma unroll
                for (int v = 0; v < 8; ++v) {
                    se = fmaf(acc[f][nt][v], pv[nt][v], se);
                    so = fmaf(acc[f][nt][v + 8], pv[nt][v], so);
                }
                se += __shfl_xor(se, 32);
                so += __shfl_xor(so, 32);
                int od = hi ? (oe + 1) : oe;
                float sv = hi ? so : se;
                __builtin_nontemporal_store(sv, &po[(size_t)od * P_ + nt * 32 + l31]);
            }
        }
    }
#undef PF_AF
#undef SUB
}

extern "C" void kernel_launch(void* const* d_in, const int* in_sizes, int n_in,
                              void* d_out, int out_size, void* d_ws, size_t ws_size,
                              hipStream_t stream) {
    const float* x  = (const float*)d_in[0];
    const float* W  = (const float*)d_in[1];
    const float* pw = (const float*)d_in[2];
    const float* pb = (const float*)d_in[3];
    const float* cw = (const float*)d_in[4];
    const float* cb = (const float*)d_in[5];
    float* out = (float*)d_out;
    char* ws = (char*)d_ws;
    unsigned short* xt = (unsigned short*)ws;
    unsigned short* Am = (unsigned short*)(ws + OFF_A);
    float* r1   = (float*)(ws + OFF_R1);

    hipLaunchKernelGGL(k_prep, dim3(320), dim3(256), 0, stream, x, xt, pw, pb, r1, W, Am);
    hipLaunchKernelGGL(k_main, dim3(512), dim3(256), 0, stream, xt, Am, r1, cw, cb, out);
}

// Round 21
// 84.784 us; speedup vs baseline: 1.0793x; 1.0510x over previous
//
#include <hip/hip_runtime.h>

typedef __attribute__((ext_vector_type(8))) short short8;
typedef __attribute__((ext_vector_type(8))) __bf16 bf16x8;
typedef __attribute__((ext_vector_type(4))) float f32x4;

// sizes
#define B_ 4
#define C_ 64
#define H_ 128
#define W_ 128
#define P_ (H_*W_)      // 16384
#define E_ 16

// ws layout (bytes)
#define OFF_A    8652800u
#define OFF_R1   9832448u

__device__ inline unsigned short f2bf(float f) {
    union { float f; unsigned u; } v; v.f = f;
    unsigned r = v.u + 0x7FFF + ((v.u >> 16) & 1);
    return (unsigned short)(r >> 16);
}

// ---------- merged prep kernel: transpose+pad+conv1x1 (blocks 0..255, 2 rows
// each) and A3 build (blocks 256..319). ----------
// A3 element offset = (g*72 + ks*4 + f)*512 + lane*8 + j   (g = o>>2, f = o&3)
// value = A_orig[row = o*16 + llo][col = ks*32 + lhi*8 + j], col = tap*64 + c
__global__ __launch_bounds__(256) void k_prep(const float* __restrict__ x,
                                              unsigned short* __restrict__ xt,
                                              const float* __restrict__ pw,
                                              const float* __restrict__ pb,
                                              float* __restrict__ r1,
                                              const float* __restrict__ Wsrc,
                                              unsigned short* __restrict__ A) {
    __shared__ float smem[9216];
    int t = threadIdx.x;
    if (blockIdx.x < 256) {
        // ---- transpose + pad + conv1x1+relu, two image rows per block ----
        float* lpw = smem;          // [1024]
        float* lpb = smem + 1024;   // [16]
        for (int lin = t; lin < 1024; lin += 256) lpw[lin] = pw[lin];
        if (t < 16) lpb[t] = pb[t];
        __syncthreads();

        int rowid = blockIdx.x * 2 + (t >> 7);
        int b = rowid >> 7, y = rowid & 127;
        int tt = t & 127; // x coordinate

        const float* src = x + (size_t)b * C_ * P_ + y * W_ + tt;
        unsigned short* dst = xt + ((size_t)(b * 130 + y + 1) * 130 + tt + 1) * 64;
        float s[16];
#pragma unroll
        for (int e = 0; e < 16; ++e) s[e] = lpb[e];
#pragma unroll
        for (int i = 0; i < 8; ++i) {
            short8 v;
#pragma unroll
            for (int j = 0; j < 8; ++j) {
                float xv = src[(size_t)(i * 8 + j) * P_];
                v[j] = (short)f2bf(xv);
#pragma unroll
                for (int e = 0; e < 16; ++e) s[e] = fmaf(lpw[e * 64 + i * 8 + j], xv, s[e]);
            }
            ((short8*)dst)[i] = v;
        }
        float* rd = r1 + (size_t)b * 16 * P_ + y * 128 + tt;
#pragma unroll
        for (int e = 0; e < 16; ++e) rd[(size_t)e * P_] = fmaxf(s[e], 0.f);

        short8 z = {0,0,0,0,0,0,0,0};
        if (tt < 16) {
            int col = (tt >> 3) * 129, i = tt & 7;
            unsigned short* bp = xt + ((size_t)(b * 130 + y + 1) * 130 + col) * 64;
            ((short8*)bp)[i] = z;
        }
        if (y == 0 || y == 127) {
            int prow = (y == 0) ? 0 : 129;
            unsigned short* rp = xt + (size_t)(b * 130 + prow) * 130 * 64;
            for (int ci = tt; ci < 1040; ci += 128) ((short8*)rp)[ci] = z;
        }
    } else {
        // ---- A3 build: o = blockIdx - 256 ----
        int o = blockIdx.x - 256;
        const float* src = Wsrc + (size_t)o * 9216; // per o: [j'=c*9+tap][e]
        for (int lin = t; lin < 9216; lin += 256) smem[lin] = src[lin];
        __syncthreads();
        int g = o >> 2, f = o & 3;
        unsigned short* dst = A + ((size_t)g * 72 + f) * 512;
        for (int lin = t; lin < 9216; lin += 256) {
            int ks = lin >> 9, rem = lin & 511;
            int lane = rem >> 3, j = rem & 7;
            int llo = lane & 15, lhi = lane >> 4;
            int col = ks * 32 + lhi * 8 + j;
            int tap = col >> 6, c = col & 63;
            dst[(size_t)ks * 2048 + rem] = f2bf(smem[(c * 9 + tap) * 16 + llo]);
        }
    }
}

// ---------- main fused kernel ----------
// R16 structure (fused pred2 prologue, fragment-linear A3, acc[4][8],
// setprio, 2 blocks/CU). R21 (= R20 with element/byte units FIXED):
//  (1) af base = wave-uniform pointer (readfirstlane), bumped 2048 ELEMENTS
//      (one ks) per half-step via SALU; af loads are saddr + imm (f*1024 B
//      <= 3072) -> no per-load 64-bit VGPR address arithmetic.
//  (2) parald padded to stride 132 floats: epilogue pvv reads 2-way (free)
//      instead of 4-way (was 524K conflict cycles).
__global__ __launch_bounds__(256, 2) void k_main(const unsigned short* __restrict__ xt,
                                                 const unsigned short* __restrict__ A,
                                                 const float* __restrict__ r1,
                                                 const float* __restrict__ cw,
                                                 const float* __restrict__ cb,
                                                 float* __restrict__ out) {
    __shared__ unsigned short lds[3 * 130 * 64]; // 49,920 B (xt rows)
    __shared__ float lcw2[2304];                 // cw as [ep][tap][e]
    __shared__ float parald[16 * 132];           // para, padded stride 132
    int r = blockIdx.x;
    int xcd = r & 7;
    int yl = r >> 3;            // [0,64)
    int rowid = xcd * 64 + yl;  // contiguous 64-row slab per XCD
    int b = rowid >> 7, y = rowid & 127;

    int tid = threadIdx.x;
    int wave = tid >> 6, lane = tid & 63, lhi = lane >> 4, llo = lane & 15;

    // stage 3 padded xt rows (y..y+2), swizzle byte ^= ((xx&7)<<4)
    const unsigned short* xrow = xt + (size_t)(b * 130 + y) * 130 * 64;
    for (int ci = tid; ci < 3120; ci += 256) {
        int row = ci / 1040, rem = ci - row * 1040;
        int xx = rem >> 3, cc = rem & 7;
        short8 v = *(const short8*)(xrow + ((size_t)row * 130 + xx) * 64 + cc * 8);
        int lb = row * 16640 + xx * 128 + ((cc * 16) ^ ((xx & 7) << 4));
        *(short8*)((char*)lds + lb) = v;
    }
    // stage cw re-laid: lcw2[(ep*9+tap)*16 + e] = cw[(e*16+ep)*9 + tap]
    for (int lin = tid; lin < 2304; lin += 256) {
        int ep = lin / 144, rem = lin - ep * 144;
        int tap = rem >> 4, e = rem & 15;
        lcw2[lin] = cw[(e * 16 + ep) * 9 + tap];
    }
    __syncthreads();

    // ---- fused pred2: para[e][px] for row y, 2 threads/px (8 e's each) ----
    {
        int px = tid & 127, eg = tid >> 7;
        const float* r1b = r1 + (size_t)b * 16 * P_;
        float s[8];
#pragma unroll
        for (int ee = 0; ee < 8; ++ee) s[ee] = cb[eg * 8 + ee];
        for (int dy = 0; dy < 3; ++dy) {
            int yy = y + dy - 1;
            if (yy < 0 || yy > 127) continue;
            for (int dx = 0; dx < 3; ++dx) {
                int xx = px + dx - 1;
                if (xx < 0 || xx > 127) continue;
                int tap = dy * 3 + dx;
                const float* rq = r1b + yy * 128 + xx;
                const float* cwt = lcw2 + tap * 16 + eg * 8;
#pragma unroll
                for (int ep = 0; ep < 16; ++ep) {
                    float v = rq[(size_t)ep * P_];
                    const float* cc = cwt + ep * 144;
#pragma unroll
                    for (int ee = 0; ee < 8; ++ee) s[ee] = fmaf(cc[ee], v, s[ee]);
                }
            }
        }
#pragma unroll
        for (int ee = 0; ee < 8; ++ee) parald[(eg * 8 + ee) * 132 + px] = s[ee];
    }
    __syncthreads();

    float* po = out + (size_t)b * 64 * P_ + y * 128;

    // precomputed LDS read vaddrs: qv[parity][kw]; full addr = qv + kh*16640 + pg*2048
    int qv[2][3];
#pragma unroll
    for (int kw = 0; kw < 3; ++kw) {
        int rowi = llo + kw;
        int base0 = rowi * 128 + ((lhi * 16) ^ ((rowi & 7) << 4));
        qv[0][kw] = base0;
        qv[1][kw] = base0 ^ 64;
    }
    const char* ldsc = (const char*)lds;
    int alo = lane * 8; // per-lane ELEMENT offset within a 512-elem frag row

// prologue af load (ks at current base): element offsets f*512 (imm f*1024 B)
#define PF_AF0(dst) do { \
    _Pragma("unroll") \
    for (int f_ = 0; f_ < 4; ++f_) \
        dst[f_] = *(const bf16x8*)(Ab + alo + f_ * 512); \
    __builtin_amdgcn_sched_barrier(0); \
} while (0)

// one half-body: bump base one ks (2048 elems, SALU), prefetch that ks into
// AFP (imm = f*1024 B <= 3072), compute with AFU.
#define HALF(AFU, AFP, PAR, KW) do { \
    Ab += 2048; \
    _Pragma("unroll") \
    for (int f_ = 0; f_ < 4; ++f_) \
        AFP[f_] = *(const bf16x8*)(Ab + alo + f_ * 512); \
    __builtin_amdgcn_sched_barrier(0); \
    const char* bp = bprow + qv[PAR][KW]; \
    bf16x8 bf[8]; \
    _Pragma("unroll") \
    for (int pg_ = 0; pg_ < 8; ++pg_) \
        bf[pg_] = *(const bf16x8*)(bp + pg_ * 2048); \
    __builtin_amdgcn_s_setprio(1); \
    _Pragma("unroll") \
    for (int f_ = 0; f_ < 4; ++f_) \
    _Pragma("unroll") \
    for (int pg_ = 0; pg_ < 8; ++pg_) \
        acc[f_][pg_] = __builtin_amdgcn_mfma_f32_16x16x32_bf16(AFU[f_], bf[pg_], acc[f_][pg_], 0, 0, 0); \
    __builtin_amdgcn_s_setprio(0); \
} while (0)

#pragma unroll 1
    for (int chunk = 0; chunk < 4; ++chunk) {
        int obase = chunk * 16 + wave * 4;
        int gu = __builtin_amdgcn_readfirstlane(chunk * 4 + wave); // uniform g
        const unsigned short* Ab = A + (size_t)gu * 36864; // g-slice base (elems)

        f32x4 acc[4][8];
#pragma unroll
        for (int f = 0; f < 4; ++f)
#pragma unroll
            for (int pg = 0; pg < 8; ++pg) acc[f][pg] = (f32x4){0.f, 0.f, 0.f, 0.f};

        bf16x8 afA[4], afB[4];
        PF_AF0(afA); // ks=0

#pragma unroll 1
        for (int kh = 0; kh < 3; ++kh) {
            const char* bprow = ldsc + kh * 16640;
            // 6 halves: (par,kw) = (0,0)(1,0)(0,1)(1,1)(0,2)(1,2); each
            // prefetches the next ks. The last half of kh=2 prefetches ks=18,
            // which is the next g-slice (or, for g=15, the start of the r1
            // region) -- in-ws overread, never consumed.
            HALF(afA, afB, 0, 0);
            HALF(afB, afA, 1, 0);
            HALF(afA, afB, 0, 1);
            HALF(afB, afA, 1, 1);
            HALF(afA, afB, 0, 2);
            HALF(afB, afA, 1, 2);
        }

        // epilogue: multiply rows (e) by para[e,p] (padded LDS), reduce over e
        float pvv[8][4];
#pragma unroll
        for (int pg = 0; pg < 8; ++pg)
#pragma unroll
            for (int rr = 0; rr < 4; ++rr)
                pvv[pg][rr] = parald[(lhi * 4 + rr) * 132 + pg * 16 + llo];

#pragma unroll
        for (int f = 0; f < 4; ++f) {
            int o = obase + f;
#pragma unroll
            for (int pg = 0; pg < 8; ++pg) {
                float s = acc[f][pg][0] * pvv[pg][0] + acc[f][pg][1] * pvv[pg][1] +
                          acc[f][pg][2] * pvv[pg][2] + acc[f][pg][3] * pvv[pg][3];
                s += __shfl_xor(s, 16);
                s += __shfl_xor(s, 32);
                if (lhi == 0)
                    __builtin_nontemporal_store(s, &po[(size_t)o * P_ + pg * 16 + llo]);
            }
        }
    }
#undef PF_AF0
#undef HALF
}

extern "C" void kernel_launch(void* const* d_in, const int* in_sizes, int n_in,
                              void* d_out, int out_size, void* d_ws, size_t ws_size,
                              hipStream_t stream) {
    const float* x  = (const float*)d_in[0];
    const float* W  = (const float*)d_in[1];
    const float* pw = (const float*)d_in[2];
    const float* pb = (const float*)d_in[3];
    const float* cw = (const float*)d_in[4];
    const float* cb = (const float*)d_in[5];
    float* out = (float*)d_out;
    char* ws = (char*)d_ws;
    unsigned short* xt = (unsigned short*)ws;
    unsigned short* Am = (unsigned short*)(ws + OFF_A);
    float* r1   = (float*)(ws + OFF_R1);

    hipLaunchKernelGGL(k_prep, dim3(320), dim3(256), 0, stream, x, xt, pw, pb, r1, W, Am);
    hipLaunchKernelGGL(k_main, dim3(512), dim3(256), 0, stream, xt, Am, r1, cw, cb, out);
}